// Round 1
// baseline (1178.951 us; speedup 1.0000x reference)
//
#include <hip/hip_runtime.h>

#define GRIDD 64
#define NN 4096
#define BB 8
#define BN 32768
#define HID 64
#define HEADS 4
#define IN_DIM 12

// ---------------- workspace layout (floats) ----------------
// XL   : BN*256  @ 0
// AS0  : BN*4    @ 8388608
// AD0  : BN*4    @ 8519680
// AS1  : BN*4    @ 8650752
// AD1  : BN*4    @ 8781824
// H    : BN*64   @ 8912896
// HIN  : BN*64   @ 11010048
// ACC  : BN*64   @ 13107200
// CAS  : 256     @ 15204352
// CAD  : 256     @ 15204608
// CCE  : 16      @ 15204864
// total 15204880 floats (~58 MB)

__device__ __forceinline__ float sigmoidf_(float x){ return 1.f / (1.f + __expf(-x)); }

// ---- tiny precompute: As[i*4+h], Ad[i*4+h], cE[h*3+e] ----
__global__ void prep_kernel(const float* __restrict__ W_gat,
                            const float* __restrict__ att_src,
                            const float* __restrict__ att_dst,
                            const float* __restrict__ W_edge,
                            const float* __restrict__ att_edge,
                            float* __restrict__ As, float* __restrict__ Ad,
                            float* __restrict__ cE)
{
    int t = threadIdx.x;          // 256 threads
    int i = t >> 2, hh = t & 3;   // t = i*4+hh
    float s = 0.f, d = 0.f;
    for (int j = 0; j < HID; j++){
        float w = W_gat[i*256 + hh*64 + j];
        s += w * att_src[hh*64 + j];
        d += w * att_dst[hh*64 + j];
    }
    As[t] = s;
    Ad[t] = d;
    if (t < 12){
        int e = t >> 2, h2 = t & 3;
        float cc = 0.f;
        for (int k = 0; k < HID; k++)
            cc += W_edge[e*256 + h2*64 + k] * att_edge[h2*64 + k];
        cE[h2*3 + e] = cc;
    }
}

// ---- encoder: one wave per node. h = silu(x@W1+b1)@W2+b2 ; also h->hin, a_s/a_d ----
__global__ __launch_bounds__(256) void enc_kernel(
    const float* __restrict__ x,
    const float* __restrict__ W1, const float* __restrict__ b1,
    const float* __restrict__ W2, const float* __restrict__ b2,
    const float* __restrict__ As, const float* __restrict__ Ad,
    float* __restrict__ h, float* __restrict__ hin,
    float* __restrict__ a_s_o, float* __restrict__ a_d_o)
{
    __shared__ __align__(16) float sW1[IN_DIM*64];
    __shared__ __align__(16) float sW2[64*64];
    __shared__ float sb1[64], sb2[64];
    int tid = threadIdx.x;
    for (int i = tid; i < IN_DIM*64; i += 256) sW1[i] = W1[i];
    for (int i = tid; i < 64*64; i += 256) sW2[i] = W2[i];
    if (tid < 64){ sb1[tid] = b1[tid]; sb2[tid] = b2[tid]; }
    __syncthreads();
    int wid = tid >> 6, lane = tid & 63;
    int n = blockIdx.x*4 + wid;
    int b = n >> 12, cell = n & 4095;
    float xv = (lane < IN_DIM) ? x[b*(IN_DIM*NN) + lane*NN + cell] : 0.f;
    float a = sb1[lane];
    #pragma unroll
    for (int c = 0; c < IN_DIM; c++)
        a += __shfl(xv, c) * sW1[c*64 + lane];
    float t = a * sigmoidf_(a);
    float hj = sb2[lane];
    for (int i = 0; i < 64; i++)
        hj += __shfl(t, i) * sW2[i*64 + lane];
    int base = n*64 + lane;
    h[base] = hj;
    hin[base] = hj;
    // a_s / a_d of h
    float4 as4 = *(const float4*)(As + lane*4);
    float4 ad4 = *(const float4*)(Ad + lane*4);
    float p0 = hj*as4.x, p1 = hj*as4.y, p2 = hj*as4.z, p3 = hj*as4.w;
    float q0 = hj*ad4.x, q1 = hj*ad4.y, q2 = hj*ad4.z, q3 = hj*ad4.w;
    #pragma unroll
    for (int msk = 1; msk < 64; msk <<= 1){
        p0 += __shfl_xor(p0, msk); p1 += __shfl_xor(p1, msk);
        p2 += __shfl_xor(p2, msk); p3 += __shfl_xor(p3, msk);
        q0 += __shfl_xor(q0, msk); q1 += __shfl_xor(q1, msk);
        q2 += __shfl_xor(q2, msk); q3 += __shfl_xor(q3, msk);
    }
    if (lane == 0){
        a_s_o[n*4+0]=p0; a_s_o[n*4+1]=p1; a_s_o[n*4+2]=p2; a_s_o[n*4+3]=p3;
        a_d_o[n*4+0]=q0; a_d_o[n*4+1]=q1; a_d_o[n*4+2]=q2; a_d_o[n*4+3]=q3;
    }
}

// ---- X: xl = hin @ W_gat   (32768x64 @ 64x256), f32 LDS-tiled ----
__global__ __launch_bounds__(256) void xl_kernel(
    const float* __restrict__ hin, const float* __restrict__ Wg,
    float* __restrict__ xlo)
{
    __shared__ __align__(16) float sH[64*68];    // [row][k], pad 68
    __shared__ __align__(16) float sW[64*128];   // [k][j] for one col-half
    int tid = threadIdx.x;
    int row0 = blockIdx.x * 64;
    for (int i = tid; i < 64*64; i += 256){
        int rr = i >> 6, kk = i & 63;
        sH[rr*68 + kk] = hin[(row0+rr)*64 + kk];
    }
    int ty = tid >> 4, tx = tid & 15;   // 16x16; thread tile 4 rows x 8 cols
    for (int ch = 0; ch < 2; ch++){
        __syncthreads();
        for (int i = tid; i < 64*128; i += 256){
            int kk = i >> 7, j = i & 127;
            sW[kk*128 + j] = Wg[kk*256 + ch*128 + j];
        }
        __syncthreads();
        float acc[4][8];
        #pragma unroll
        for (int i = 0; i < 4; i++)
            #pragma unroll
            for (int j = 0; j < 8; j++) acc[i][j] = 0.f;
        for (int k = 0; k < 64; k++){
            float av[4];
            #pragma unroll
            for (int i = 0; i < 4; i++) av[i] = sH[(ty*4+i)*68 + k];
            float bv[8];
            *(float4*)&bv[0] = *(const float4*)&sW[k*128 + tx*8];
            *(float4*)&bv[4] = *(const float4*)&sW[k*128 + tx*8 + 4];
            #pragma unroll
            for (int i = 0; i < 4; i++)
                #pragma unroll
                for (int j = 0; j < 8; j++)
                    acc[i][j] += av[i]*bv[j];
        }
        #pragma unroll
        for (int i = 0; i < 4; i++){
            int rr = ty*4 + i;
            float4 o0, o1;
            o0.x=acc[i][0]; o0.y=acc[i][1]; o0.z=acc[i][2]; o0.w=acc[i][3];
            o1.x=acc[i][4]; o1.y=acc[i][5]; o1.z=acc[i][6]; o1.w=acc[i][7];
            float* dst = xlo + (row0+rr)*256 + ch*128 + tx*8;
            *(float4*)dst = o0;
            *(float4*)(dst+4) = o1;
        }
    }
}

// ---- F: stencil attention + head-mean + LN + silu + RK4 update. one wave per node ----
__global__ __launch_bounds__(256) void f_kernel(
    const float* __restrict__ xl,
    const float* __restrict__ a_s_i, const float* __restrict__ a_d_i,
    const float* __restrict__ x, const float* __restrict__ cE,
    const float* __restrict__ b_gat, const float* __restrict__ g_f, const float* __restrict__ bt_f,
    const float* __restrict__ As, const float* __restrict__ Ad,
    float* __restrict__ h, float* __restrict__ hin, float* __restrict__ accb,
    float* __restrict__ a_s_o, float* __restrict__ a_d_o, int stage)
{
    int tid = threadIdx.x;
    int wid = tid >> 6, lane = tid & 63;
    int n = blockIdx.x*4 + wid;
    int b = n >> 12, cell = n & 4095;
    int r = cell >> 6, c = cell & 63;
    int xbase = b*(IN_DIM*NN);
    float x0n = x[xbase + cell];

    // ---- attention logits + softmax (lanes 0..31: lane = o*4 + hh) ----
    float alpha;
    {
        int o = lane >> 2, hh = lane & 3;
        int i9 = (o < 4) ? o : o + 1;
        int dy = i9/3 - 1, dx = i9 - (i9/3)*3 - 1;
        int sr = r - dy, sc = c - dx;
        bool valid = (lane < 32) && (sr >= 0) && (sr < 64) && (sc >= 0) && (sc < 64);
        float logit = -1e30f;
        if (valid){
            int mcell = (sr << 6) + sc;
            int m = (b << 12) + mcell;
            float diff = x0n - x[xbase + mcell];
            float fdx = (float)dx, fdy = (float)dy;
            float inv = rsqrtf(fdx*fdx + fdy*fdy);
            float av = a_s_i[m*4 + hh] + a_d_i[n*4 + hh]
                     + cE[hh*3+0]*(fdx*inv) + cE[hh*3+1]*(fdy*inv) + cE[hh*3+2]*diff;
            logit = (av >= 0.f) ? av : 0.2f*av;
        }
        float m1 = logit;
        m1 = fmaxf(m1, __shfl_xor(m1, 4));
        m1 = fmaxf(m1, __shfl_xor(m1, 8));
        m1 = fmaxf(m1, __shfl_xor(m1, 16));
        float p = valid ? __expf(logit - m1) : 0.f;
        float z = p;
        z += __shfl_xor(z, 4);
        z += __shfl_xor(z, 8);
        z += __shfl_xor(z, 16);
        alpha = p / (z + 1e-16f);
    }

    // ---- weighted gather of xl over valid offsets; mean over heads fused (x0.25) ----
    float outv = 0.f;
    #pragma unroll
    for (int o = 0; o < 8; o++){
        const int i9 = (o < 4) ? o : o + 1;
        const int dy = i9/3 - 1, dx = i9%3 - 1;
        int sr = r - dy, sc = c - dx;
        if (sr < 0 || sr > 63 || sc < 0 || sc > 63) continue;   // wave-uniform
        int m = (b << 12) + (sr << 6) + sc;
        const float* xr = xl + m*256;
        float a0 = __shfl(alpha, o*4 + 0);
        float a1 = __shfl(alpha, o*4 + 1);
        float a2 = __shfl(alpha, o*4 + 2);
        float a3 = __shfl(alpha, o*4 + 3);
        outv += a0*xr[lane] + a1*xr[64+lane] + a2*xr[128+lane] + a3*xr[192+lane];
    }
    outv = 0.25f*outv + b_gat[lane];

    // ---- LayerNorm over 64 lanes + silu ----
    float s = outv;
    s += __shfl_xor(s,1); s += __shfl_xor(s,2); s += __shfl_xor(s,4);
    s += __shfl_xor(s,8); s += __shfl_xor(s,16); s += __shfl_xor(s,32);
    float mean = s * 0.015625f;
    float dv = outv - mean;
    float v2 = dv*dv;
    v2 += __shfl_xor(v2,1); v2 += __shfl_xor(v2,2); v2 += __shfl_xor(v2,4);
    v2 += __shfl_xor(v2,8); v2 += __shfl_xor(v2,16); v2 += __shfl_xor(v2,32);
    float rstd = rsqrtf(v2*0.015625f + 1e-5f);
    float y = dv*rstd*g_f[lane] + bt_f[lane];
    float kv = y * sigmoidf_(y);

    // ---- RK4 stage update ----
    int base = n*64 + lane;
    float hold = h[base];
    float hnext;
    if (stage == 0){
        accb[base] = kv;
        hnext = hold + 0.125f*kv;           // h + 0.5*dt*k1, dt=0.25
        hin[base] = hnext;
    } else if (stage == 1){
        accb[base] += 2.f*kv;
        hnext = hold + 0.125f*kv;
        hin[base] = hnext;
    } else if (stage == 2){
        accb[base] += 2.f*kv;
        hnext = hold + 0.25f*kv;
        hin[base] = hnext;
    } else {
        hnext = hold + (0.25f/6.f)*(accb[base] + kv);
        h[base] = hnext;
        hin[base] = hnext;
    }

    // ---- a_s / a_d of the next stage input ----
    float4 as4 = *(const float4*)(As + lane*4);
    float4 ad4 = *(const float4*)(Ad + lane*4);
    float p0 = hnext*as4.x, p1 = hnext*as4.y, p2 = hnext*as4.z, p3 = hnext*as4.w;
    float q0 = hnext*ad4.x, q1 = hnext*ad4.y, q2 = hnext*ad4.z, q3 = hnext*ad4.w;
    #pragma unroll
    for (int msk = 1; msk < 64; msk <<= 1){
        p0 += __shfl_xor(p0, msk); p1 += __shfl_xor(p1, msk);
        p2 += __shfl_xor(p2, msk); p3 += __shfl_xor(p3, msk);
        q0 += __shfl_xor(q0, msk); q1 += __shfl_xor(q1, msk);
        q2 += __shfl_xor(q2, msk); q3 += __shfl_xor(q3, msk);
    }
    if (lane == 0){
        a_s_o[n*4+0]=p0; a_s_o[n*4+1]=p1; a_s_o[n*4+2]=p2; a_s_o[n*4+3]=p3;
        a_d_o[n*4+0]=q0; a_d_o[n*4+1]=q1; a_d_o[n*4+2]=q2; a_d_o[n*4+3]=q3;
    }
}

// ---- head: out = (silu(LN(h))@W_h1 -> silu) @ W_h2, fire override. one wave per node ----
__global__ __launch_bounds__(256) void head_kernel(
    const float* __restrict__ h, const float* __restrict__ x,
    const float* __restrict__ g_h, const float* __restrict__ bt_h,
    const float* __restrict__ W_h1, const float* __restrict__ b_h1,
    const float* __restrict__ W_h2, const float* __restrict__ b_h2,
    float* __restrict__ out)
{
    __shared__ __align__(16) float sW1[4096];
    __shared__ float sw2[64], sg[64], sbt[64], sb1[64];
    int tid = threadIdx.x;
    for (int i = tid; i < 4096; i += 256) sW1[i] = W_h1[i];
    if (tid < 64){ sw2[tid]=W_h2[tid]; sg[tid]=g_h[tid]; sbt[tid]=bt_h[tid]; sb1[tid]=b_h1[tid]; }
    __syncthreads();
    int wid = tid >> 6, lane = tid & 63;
    int n = blockIdx.x*4 + wid;
    float hv = h[n*64 + lane];
    float s = hv;
    s += __shfl_xor(s,1); s += __shfl_xor(s,2); s += __shfl_xor(s,4);
    s += __shfl_xor(s,8); s += __shfl_xor(s,16); s += __shfl_xor(s,32);
    float mean = s * 0.015625f;
    float dv = hv - mean;
    float v2 = dv*dv;
    v2 += __shfl_xor(v2,1); v2 += __shfl_xor(v2,2); v2 += __shfl_xor(v2,4);
    v2 += __shfl_xor(v2,8); v2 += __shfl_xor(v2,16); v2 += __shfl_xor(v2,32);
    float rstd = rsqrtf(v2*0.015625f + 1e-5f);
    float ln = dv*rstd*sg[lane] + sbt[lane];
    // z_j = silu(b1[j] + sum_i ln_i * W1[i][j]) at j=lane
    float a = sb1[lane];
    for (int i = 0; i < 64; i++)
        a += __shfl(ln, i) * sW1[i*64 + lane];
    float z = a * sigmoidf_(a);
    float lg = z * sw2[lane];
    lg += __shfl_xor(lg,1); lg += __shfl_xor(lg,2); lg += __shfl_xor(lg,4);
    lg += __shfl_xor(lg,8); lg += __shfl_xor(lg,16); lg += __shfl_xor(lg,32);
    if (lane == 0){
        float logit = lg + b_h2[0];
        int b = n >> 12, cell = n & 4095;
        float fire = x[b*(IN_DIM*NN) + cell];
        out[n] = (fire > 0.5f) ? fmaxf(logit, 6.f) : logit;
    }
}

extern "C" void kernel_launch(void* const* d_in, const int* in_sizes, int n_in,
                              void* d_out, int out_size, void* d_ws, size_t ws_size,
                              hipStream_t stream)
{
    const float* x       = (const float*)d_in[0];
    // d_in[1]=edge_index, d_in[2]=edge_dirs -- derived analytically, unused
    const float* W_enc1  = (const float*)d_in[3];
    const float* b_enc1  = (const float*)d_in[4];
    const float* W_enc2  = (const float*)d_in[5];
    const float* b_enc2  = (const float*)d_in[6];
    const float* W_gat   = (const float*)d_in[7];
    const float* att_src = (const float*)d_in[8];
    const float* att_dst = (const float*)d_in[9];
    const float* W_edge  = (const float*)d_in[10];
    const float* att_edge= (const float*)d_in[11];
    const float* b_gat   = (const float*)d_in[12];
    const float* g_f     = (const float*)d_in[13];
    const float* bt_f    = (const float*)d_in[14];
    const float* g_h     = (const float*)d_in[15];
    const float* bt_h    = (const float*)d_in[16];
    const float* W_h1    = (const float*)d_in[17];
    const float* b_h1    = (const float*)d_in[18];
    const float* W_h2    = (const float*)d_in[19];
    const float* b_h2    = (const float*)d_in[20];

    float* ws  = (float*)d_ws;
    float* XL  = ws;
    float* AS0 = ws + 8388608;
    float* AD0 = ws + 8519680;
    float* AS1 = ws + 8650752;
    float* AD1 = ws + 8781824;
    float* H   = ws + 8912896;
    float* HIN = ws + 11010048;
    float* ACC = ws + 13107200;
    float* CAS = ws + 15204352;
    float* CAD = ws + 15204608;
    float* CCE = ws + 15204864;
    float* out = (float*)d_out;

    prep_kernel<<<1, 256, 0, stream>>>(W_gat, att_src, att_dst, W_edge, att_edge, CAS, CAD, CCE);
    enc_kernel<<<8192, 256, 0, stream>>>(x, W_enc1, b_enc1, W_enc2, b_enc2, CAS, CAD,
                                         H, HIN, AS0, AD0);

    float* asi = AS0; float* adi = AD0;
    float* aso = AS1; float* ado = AD1;
    for (int step = 0; step < 4; step++){
        for (int st = 0; st < 4; st++){
            xl_kernel<<<512, 256, 0, stream>>>(HIN, W_gat, XL);
            f_kernel<<<8192, 256, 0, stream>>>(XL, asi, adi, x, CCE,
                                               b_gat, g_f, bt_f, CAS, CAD,
                                               H, HIN, ACC, aso, ado, st);
            float* t;
            t = asi; asi = aso; aso = t;
            t = adi; adi = ado; ado = t;
        }
    }

    head_kernel<<<8192, 256, 0, stream>>>(H, x, g_h, bt_h, W_h1, b_h1, W_h2, b_h2, out);
}